// Round 4
// baseline (151.109 us; speedup 1.0000x reference)
//
#include <hip/hip_runtime.h>
#include <hip/hip_bf16.h>
#include <math.h>

#define Fdim 40
#define Edim 64
#define K2   128
#define Tdim 2
#define EPSV 1e-5f

typedef __attribute__((ext_vector_type(8))) short short8;
typedef __attribute__((ext_vector_type(4))) float f32x4;

__device__ __forceinline__ short f2b(float f) {
    unsigned u = __builtin_bit_cast(unsigned, f);
    unsigned r = (u + 0x7fffu + ((u >> 16) & 1u)) >> 16;
    return (short)r;
}
__device__ __forceinline__ float b2f(short h) {
    unsigned u = ((unsigned)(unsigned short)h) << 16;
    return __builtin_bit_cast(float, u);
}
__device__ __forceinline__ f32x4 mfma16(short8 a, short8 b, f32x4 c) {
    return __builtin_amdgcn_mfma_f32_16x16x32_bf16(a, b, c, 0, 0, 0);
}
// swizzled byte offset within a [48][64] bf16 buffer (row stride 128 B)
__device__ __forceinline__ int swz(int f, int e2 /*byte col*/) {
    return (f * 128 + e2) ^ ((f & 7) << 4);
}

// ws layout (shorts):
//   adjT bf16 [2][48][64]   : 0      .. 6144
//   WT   bf16 [2][64][128]  : 6144   .. 22528
//   gwT  bf16 [48][2560]    : 22528  .. 145408
//   bnS  f32  [2][40][128]  : float idx 0 at short 145408
//   bnO  f32  [2][40][128]  : float idx 10240       (total 372736 B)

// ---------------------------------------------------------------------------
__global__ void adj_kernel(const float* __restrict__ masker,
                           const float* __restrict__ ln_gamma,
                           const float* __restrict__ ln_beta,
                           short* __restrict__ adjT) {
    const int t = blockIdx.x;
    const int tid = threadIdx.x;
    __shared__ float araw[Fdim][Fdim];

    for (int i = tid; i < Fdim * Fdim; i += 64) {
        int g = i / Fdim, ff = i % Fdim;
        const float* mb = masker + t * (3 * Fdim * Fdim) + g * Fdim + ff;
        float p = mb[0] * mb[Fdim * Fdim] * mb[2 * Fdim * Fdim];
        araw[g][ff] = p > 0.f ? p : 0.f;
    }
    __syncthreads();

    const int f = tid;
    if (f < 40) {
        float mu = 0.f, m2 = 0.f;
        #pragma unroll
        for (int g = 0; g < Fdim; ++g) {
            float v = araw[g][f];
            mu += v; m2 += v * v;
        }
        mu *= (1.f / Fdim); m2 *= (1.f / Fdim);
        float inv = rsqrtf(m2 - mu * mu + EPSV);

        float logits[Fdim];
        float mx = -1e30f;
        #pragma unroll
        for (int g = 0; g < Fdim; ++g) {
            float v = araw[g][f];
            float l = (v - mu) * inv * ln_gamma[g] + ln_beta[g];
            if (v == 0.f) l += -1e9f;
            if (g == f) l += 1.f;
            logits[g] = l;
            mx = fmaxf(mx, l);
        }
        float den = 0.f;
        #pragma unroll
        for (int g = 0; g < Fdim; ++g) {
            float p = expf(logits[g] - mx);
            logits[g] = p;
            den += p;
        }
        float rden = 1.f / den;
        short* row = adjT + t * 3072 + f * 64;   // adjT[t][f][g]
        #pragma unroll
        for (int g = 0; g < Fdim; ++g) {
            float msk = (araw[g][f] != 0.f) ? 1.f : 0.f;
            row[g] = f2b(logits[g] * rden * msk);
        }
        for (int g = Fdim; g < 64; ++g) row[g] = 0;
    } else if (f < 48) {
        short* row = adjT + t * 3072 + f * 64;
        for (int g = 0; g < 64; ++g) row[g] = 0;
    }
}

// ---------------------------------------------------------------------------
__global__ void prep_kernel(const float* __restrict__ w_t,
                            const float* __restrict__ gate_w,
                            const float* __restrict__ bn_gamma,
                            const float* __restrict__ bn_beta,
                            const float* __restrict__ bn_mean,
                            const float* __restrict__ bn_var,
                            short* __restrict__ WT,
                            short* __restrict__ gwT,
                            float* __restrict__ bnS,
                            float* __restrict__ bnO) {
    int i = blockIdx.x * 256 + threadIdx.x;
    if (i < 16384) {
        int t = i >> 13, r = i & 8191, e = r >> 7, k = r & 127;
        WT[i] = f2b(w_t[t * 8192 + k * 64 + e]);
    } else if (i < 139264) {
        int j = i - 16384;
        int fo = j / 2560, k = j - fo * 2560;
        gwT[j] = (fo < 40) ? f2b(gate_w[k * 40 + fo]) : (short)0;
    } else if (i < 149504) {
        int j = i - 139264;
        float s = bn_gamma[j] * rsqrtf(bn_var[j] + EPSV);
        bnS[j] = s;
        bnO[j] = bn_beta[j] - bn_mean[j] * s;
    }
}

// ---------------------------------------------------------------------------
// main: 512 thr / 8 waves; wave w = (s = w>>1, t = w&1), sample = blockIdx*4+s.
// Per-wave LDS buf 6144 B: [48][64] bf16 swizzled (nei -> xcur in place).
// Barrier-free through phases N and M; 3 barriers in gate/output tail.
// ---------------------------------------------------------------------------
__global__ __launch_bounds__(512, 4) void main_kernel(
    const float* __restrict__ x,
    const short* __restrict__ adjT,
    const short* __restrict__ WT,
    const short* __restrict__ gwT,
    const float* __restrict__ bnS,
    const float* __restrict__ bnO,
    const float* __restrict__ b_t,
    const float* __restrict__ gate_b,
    float* __restrict__ out)
{
    extern __shared__ char smem[];
    const int tid = threadIdx.x;
    const int w = tid >> 6, lane = tid & 63;
    const int er = lane & 15, q = lane >> 4;
    const int s = w >> 1, t = w & 1;
    const int bbase = blockIdx.x * 4;

    char* buf = smem + w * 6144;                 // this wave's [48][64] swz buf
    f32x4* gred = (f32x4*)(smem + 49152);        // [24][64] f32x4
    float* g_lds = (float*)(smem + 73728);       // [8][40] f32

    const float* xb    = x + (size_t)(bbase + s) * 2560;
    const short* adjTt = adjT + t * 3072;
    const short* WTt   = WT + t * 8192;
    const float* bnSt  = bnS + t * 5120;
    const float* bnOt  = bnO + t * 5120;
    const float* btt   = b_t + t * 2560;

    // ---- build B-fragments of x (k = g): direct global scalar loads (L1-hot)
    short8 Bf[2][4];
    #pragma unroll
    for (int nt = 0; nt < 4; ++nt) {
        const float* xe = xb + nt * 16 + er;
        short8 v0;
        #pragma unroll
        for (int j = 0; j < 8; ++j) v0[j] = f2b(xe[(q * 8 + j) * 64]);
        Bf[0][nt] = v0;
        short8 v1 = {0, 0, 0, 0, 0, 0, 0, 0};
        if (q == 0) {
            #pragma unroll
            for (int j = 0; j < 8; ++j) v1[j] = f2b(xe[(32 + j) * 64]);
        }
        Bf[1][nt] = v1;
    }

    // ---------------- phase N: nei = adjT * x, BN2 fused on store
    #pragma unroll
    for (int mt = 0; mt < 3; ++mt) {
        const short* arow = adjTt + (mt * 16 + er) * 64 + q * 8;
        short8 A0 = *(const short8*)(arow);
        short8 A1 = *(const short8*)(arow + 32);
        #pragma unroll
        for (int nt = 0; nt < 4; ++nt) {
            f32x4 z = {0.f, 0.f, 0.f, 0.f};
            z = mfma16(A0, Bf[0][nt], z);
            f32x4 acc = mfma16(A1, Bf[1][nt], z);
            #pragma unroll
            for (int r = 0; r < 4; ++r) {
                int f = mt * 16 + q * 4 + r;
                if (f < 40) {
                    int e = nt * 16 + er;
                    int ci = f * 128 + 64 + e;
                    float vv = acc[r] * bnSt[ci] + bnOt[ci];
                    *(short*)(buf + swz(f, e * 2)) = f2b(vv);
                }
            }
        }
    }

    // ---------------- phase M: xcur = BN(concat(x,nei)) @ W + b (in place)
    #pragma unroll
    for (int mt = 0; mt < 3; ++mt) {
        f32x4 acc[4];
        #pragma unroll
        for (int nt = 0; nt < 4; ++nt) { f32x4 z = {0.f,0.f,0.f,0.f}; acc[nt] = z; }
        #pragma unroll
        for (int kt = 0; kt < 4; ++kt) {
            short8 A;
            if (kt < 2) {
                int f = mt * 16 + er;
                if (f < 40) {
                    int kb = kt * 32 + q * 8;
                    const float4* xp = (const float4*)(xb + f * 64 + kb);
                    float4 x0 = xp[0], x1 = xp[1];
                    const float4* sp = (const float4*)(bnSt + f * 128 + kb);
                    const float4* op = (const float4*)(bnOt + f * 128 + kb);
                    float4 s0 = sp[0], s1 = sp[1], o0 = op[0], o1 = op[1];
                    A[0] = f2b(x0.x * s0.x + o0.x);
                    A[1] = f2b(x0.y * s0.y + o0.y);
                    A[2] = f2b(x0.z * s0.z + o0.z);
                    A[3] = f2b(x0.w * s0.w + o0.w);
                    A[4] = f2b(x1.x * s1.x + o1.x);
                    A[5] = f2b(x1.y * s1.y + o1.y);
                    A[6] = f2b(x1.z * s1.z + o1.z);
                    A[7] = f2b(x1.w * s1.w + o1.w);
                } else {
                    short8 za = {0,0,0,0,0,0,0,0};
                    A = za;
                }
            } else {
                int f = mt * 16 + er;
                A = *(const short8*)(buf + swz(f, (kt - 2) * 64 + q * 16));
            }
            #pragma unroll
            for (int nt = 0; nt < 4; ++nt) {
                short8 B = *(const short8*)(WTt + (nt * 16 + er) * 128 + kt * 32 + q * 8);
                acc[nt] = mfma16(A, B, acc[nt]);
            }
        }
        #pragma unroll
        for (int nt = 0; nt < 4; ++nt) {
            #pragma unroll
            for (int r = 0; r < 4; ++r) {
                int f = mt * 16 + q * 4 + r;
                if (f < 40) {
                    int e = nt * 16 + er;
                    float vv = acc[nt][r] + btt[f * 64 + e];
                    *(short*)(buf + swz(f, e * 2)) = f2b(vv);
                }
            }
        }
    }

    __syncthreads();

    // ---------------- gate: M=16 (8 st used), K=2560 split 8 ways over waves
    {
        f32x4 g0 = {0.f,0.f,0.f,0.f}, g1 = g0, g2 = g0;
        const char* abase = smem + (er & 7) * 6144;
        #pragma unroll
        for (int kk = 0; kk < 10; ++kk) {
            int step = w * 10 + kk;
            int k0 = step * 32;
            int f = k0 >> 6;
            short8 A = *(const short8*)(abase + swz(f, (k0 & 63) * 2 + q * 16));
            const short* gwp = gwT + k0 + q * 8;
            g0 = mfma16(A, *(const short8*)(gwp + er * 2560), g0);
            g1 = mfma16(A, *(const short8*)(gwp + (16 + er) * 2560), g1);
            g2 = mfma16(A, *(const short8*)(gwp + (32 + er) * 2560), g2);
        }
        gred[(w * 3 + 0) * 64 + lane] = g0;
        gred[(w * 3 + 1) * 64 + lane] = g1;
        gred[(w * 3 + 2) * 64 + lane] = g2;
    }
    __syncthreads();

    // reduce 8 wave partials; thread (nt, lane) for tid < 192
    if (tid < 192) {
        int nt = tid >> 6, l = tid & 63;
        int rer = l & 15, rq = l >> 4;
        f32x4 v = gred[(0 * 3 + nt) * 64 + l];
        #pragma unroll
        for (int ww = 1; ww < 8; ++ww) v += gred[(ww * 3 + nt) * 64 + l];
        int fo = nt * 16 + rer;
        if (rq < 2 && fo < 40) {
            float gb = gate_b[fo];
            #pragma unroll
            for (int r = 0; r < 4; ++r)
                g_lds[(rq * 4 + r) * 40 + fo] = v[r] + gb;
        }
    }
    __syncthreads();

    // ---------------- final: softmax over f + weighted sum; thread = (st, e)
    {
        int st = tid >> 6, e = tid & 63;
        const float* gr = g_lds + st * 40;
        const char* bufr = smem + st * 6144;
        float m = gr[0];
        #pragma unroll
        for (int f2 = 1; f2 < 40; ++f2) m = fmaxf(m, gr[f2]);
        float den = 0.f, o = 0.f;
        #pragma unroll
        for (int f2 = 0; f2 < 40; ++f2) {
            float p = __expf(gr[f2] - m);
            den += p;
            short xv = *(const short*)(bufr + swz(f2, e * 2));
            o += p * b2f(xv);
        }
        out[(size_t)(bbase * 2 + st) * 64 + e] = o / den;
    }
}

extern "C" void kernel_launch(void* const* d_in, const int* in_sizes, int n_in,
                              void* d_out, int out_size, void* d_ws, size_t ws_size,
                              hipStream_t stream) {
    (void)in_sizes; (void)n_in; (void)out_size; (void)ws_size;
    const float* x        = (const float*)d_in[0];
    const float* masker   = (const float*)d_in[1];
    const float* ln_gamma = (const float*)d_in[2];
    const float* ln_beta  = (const float*)d_in[3];
    const float* w_t      = (const float*)d_in[4];
    const float* b_t      = (const float*)d_in[5];
    const float* bn_gamma = (const float*)d_in[6];
    const float* bn_beta  = (const float*)d_in[7];
    const float* bn_mean  = (const float*)d_in[8];
    const float* bn_var   = (const float*)d_in[9];
    const float* gate_w   = (const float*)d_in[10];
    const float* gate_b   = (const float*)d_in[11];
    float* out = (float*)d_out;

    short* adjT = (short*)d_ws;
    short* WT   = adjT + 6144;
    short* gwT  = WT + 16384;
    float* bnS  = (float*)(gwT + 122880);
    float* bnO  = bnS + 10240;

    adj_kernel<<<Tdim, 64, 0, stream>>>(masker, ln_gamma, ln_beta, adjT);
    prep_kernel<<<584, 256, 0, stream>>>(w_t, gate_w, bn_gamma, bn_beta, bn_mean,
                                         bn_var, WT, gwT, bnS, bnO);

    constexpr int SMEM_BYTES = 8 * 6144 + 24 * 64 * 16 + 8 * 40 * 4;  // 75008
    (void)hipFuncSetAttribute((const void*)main_kernel,
                              hipFuncAttributeMaxDynamicSharedMemorySize, SMEM_BYTES);
    main_kernel<<<1024, 512, SMEM_BYTES, stream>>>(
        x, adjT, WT, gwT, bnS, bnO, b_t, gate_b, out);
}

// Round 5
// 150.935 us; speedup vs baseline: 1.0012x; 1.0012x over previous
//
#include <hip/hip_runtime.h>
#include <hip/hip_bf16.h>
#include <math.h>

#define Fdim 40
#define Edim 64
#define K2   128
#define Tdim 2
#define EPSV 1e-5f

typedef __attribute__((ext_vector_type(8))) short short8;
typedef __attribute__((ext_vector_type(4))) float f32x4;

__device__ __forceinline__ short f2b(float f) {
    unsigned u = __builtin_bit_cast(unsigned, f);
    unsigned r = (u + 0x7fffu + ((u >> 16) & 1u)) >> 16;
    return (short)r;
}
__device__ __forceinline__ float b2f(short h) {
    unsigned u = ((unsigned)(unsigned short)h) << 16;
    return __builtin_bit_cast(float, u);
}
__device__ __forceinline__ f32x4 mfma16(short8 a, short8 b, f32x4 c) {
    return __builtin_amdgcn_mfma_f32_16x16x32_bf16(a, b, c, 0, 0, 0);
}
// swizzled byte offset within a [48][64] bf16 buffer (row stride 128 B)
__device__ __forceinline__ int swz(int f, int e2 /*byte col*/) {
    return (f * 128 + e2) ^ ((f & 7) << 4);
}

// ws layout:
//   adjT  bf16 [2][48][64]   : shorts 0      .. 6144
//   WT    bf16 [2][64][128]  : shorts 6144   .. 22528
//   gwT   bf16 [48][2560]    : shorts 22528  .. 145408
//   bnSx  f32  [2][40][64]   : x-half BN scale (k<64), 5120 floats
//   bnOx  f32  [2][40][64]   : 5120 floats
//   bnS2T f32  [2][64][48]   : nei-half BN scale, transposed [t][e][f], 6144
//   bnO2T f32  [2][64][48]   : 6144
//   btT   f32  [2][64][48]   : bias transposed [t][e][f], 6144
//   total 405504 B

// ---------------------------------------------------------------------------
__global__ void adj_kernel(const float* __restrict__ masker,
                           const float* __restrict__ ln_gamma,
                           const float* __restrict__ ln_beta,
                           short* __restrict__ adjT) {
    const int t = blockIdx.x;
    const int tid = threadIdx.x;
    __shared__ float araw[Fdim][Fdim];

    for (int i = tid; i < Fdim * Fdim; i += 64) {
        int g = i / Fdim, ff = i % Fdim;
        const float* mb = masker + t * (3 * Fdim * Fdim) + g * Fdim + ff;
        float p = mb[0] * mb[Fdim * Fdim] * mb[2 * Fdim * Fdim];
        araw[g][ff] = p > 0.f ? p : 0.f;
    }
    __syncthreads();

    const int f = tid;
    if (f < 40) {
        float mu = 0.f, m2 = 0.f;
        #pragma unroll
        for (int g = 0; g < Fdim; ++g) {
            float v = araw[g][f];
            mu += v; m2 += v * v;
        }
        mu *= (1.f / Fdim); m2 *= (1.f / Fdim);
        float inv = rsqrtf(m2 - mu * mu + EPSV);

        float logits[Fdim];
        float mx = -1e30f;
        #pragma unroll
        for (int g = 0; g < Fdim; ++g) {
            float v = araw[g][f];
            float l = (v - mu) * inv * ln_gamma[g] + ln_beta[g];
            if (v == 0.f) l += -1e9f;
            if (g == f) l += 1.f;
            logits[g] = l;
            mx = fmaxf(mx, l);
        }
        float den = 0.f;
        #pragma unroll
        for (int g = 0; g < Fdim; ++g) {
            float p = expf(logits[g] - mx);
            logits[g] = p;
            den += p;
        }
        float rden = 1.f / den;
        short* row = adjT + t * 3072 + f * 64;   // adjT[t][f][g]
        #pragma unroll
        for (int g = 0; g < Fdim; ++g) {
            float msk = (araw[g][f] != 0.f) ? 1.f : 0.f;
            row[g] = f2b(logits[g] * rden * msk);
        }
        for (int g = Fdim; g < 64; ++g) row[g] = 0;
    } else if (f < 48) {
        short* row = adjT + t * 3072 + f * 64;
        for (int g = 0; g < 64; ++g) row[g] = 0;
    }
}

// ---------------------------------------------------------------------------
__global__ void prep_kernel(const float* __restrict__ w_t,
                            const float* __restrict__ gate_w,
                            const float* __restrict__ bn_gamma,
                            const float* __restrict__ bn_beta,
                            const float* __restrict__ bn_mean,
                            const float* __restrict__ bn_var,
                            const float* __restrict__ b_t,
                            short* __restrict__ WT,
                            short* __restrict__ gwT,
                            float* __restrict__ bnSx,
                            float* __restrict__ bnOx,
                            float* __restrict__ bnS2T,
                            float* __restrict__ bnO2T,
                            float* __restrict__ btT) {
    int i = blockIdx.x * 256 + threadIdx.x;
    if (i < 16384) {
        int t = i >> 13, r = i & 8191, e = r >> 7, k = r & 127;
        WT[i] = f2b(w_t[t * 8192 + k * 64 + e]);
    } else if (i < 139264) {
        int j = i - 16384;
        int fo = j / 2560, k = j - fo * 2560;
        gwT[j] = (fo < 40) ? f2b(gate_w[k * 40 + fo]) : (short)0;
    } else if (i < 144384) {            // x-half BN, [t][f][k<64]
        int j = i - 139264;
        int t = j / 2560, r = j % 2560, f = r >> 6, k = r & 63;
        int src = t * 5120 + f * 128 + k;
        float s = bn_gamma[src] * rsqrtf(bn_var[src] + EPSV);
        bnSx[j] = s;
        bnOx[j] = bn_beta[src] - bn_mean[src] * s;
    } else if (i < 150528) {            // nei-half BN transposed, [t][e][f48]
        int j = i - 144384;
        int t = j / 3072, r = j % 3072, e = r / 48, f = r % 48;
        float s = 0.f, o = 0.f;
        if (f < 40) {
            int src = t * 5120 + f * 128 + 64 + e;
            s = bn_gamma[src] * rsqrtf(bn_var[src] + EPSV);
            o = bn_beta[src] - bn_mean[src] * s;
        }
        bnS2T[j] = s;
        bnO2T[j] = o;
    } else if (i < 156672) {            // bias transposed, [t][e][f48]
        int j = i - 150528;
        int t = j / 3072, r = j % 3072, e = r / 48, f = r % 48;
        btT[j] = (f < 40) ? b_t[t * 2560 + f * 64 + e] : 0.f;
    }
}

// ---------------------------------------------------------------------------
// main: 512 thr / 8 waves; wave w = (s = w>>1, t = w&1), sample = blockIdx*4+s.
// Per-wave LDS buf 6144 B: [48][64] bf16 swizzled (nei -> xcur in place).
// Barrier-free through phases N and M; 3 barriers in gate/output tail.
// ---------------------------------------------------------------------------
__global__ __launch_bounds__(512, 2) void main_kernel(
    const float* __restrict__ x,
    const short* __restrict__ adjT,
    const short* __restrict__ WT,
    const short* __restrict__ gwT,
    const float* __restrict__ bnSx,
    const float* __restrict__ bnOx,
    const float* __restrict__ bnS2T,
    const float* __restrict__ bnO2T,
    const float* __restrict__ btT,
    const float* __restrict__ gate_b,
    float* __restrict__ out)
{
    extern __shared__ char smem[];
    const int tid = threadIdx.x;
    const int w = tid >> 6, lane = tid & 63;
    const int er = lane & 15, q = lane >> 4;
    const int s = w >> 1, t = w & 1;
    const int bbase = blockIdx.x * 4;

    char* buf = smem + w * 6144;                 // this wave's [48][64] swz buf
    f32x4* gred = (f32x4*)(smem + 49152);        // [24][64] f32x4
    float* g_lds = (float*)(smem + 73728);       // [8][40] f32

    const float* xb     = x + (size_t)(bbase + s) * 2560;
    const short* adjTt  = adjT + t * 3072;
    const short* WTt    = WT + t * 8192;
    const float* bnSxt  = bnSx + t * 2560;
    const float* bnOxt  = bnOx + t * 2560;
    const float* bnS2Tt = bnS2T + t * 3072;
    const float* bnO2Tt = bnO2T + t * 3072;
    const float* btTt   = btT + t * 3072;

    // ---- build B-fragments of x (k = g): direct global scalar loads (L1-hot)
    short8 Bf[2][4];
    #pragma unroll
    for (int nt = 0; nt < 4; ++nt) {
        const float* xe = xb + nt * 16 + er;
        short8 v0;
        #pragma unroll
        for (int j = 0; j < 8; ++j) v0[j] = f2b(xe[(q * 8 + j) * 64]);
        Bf[0][nt] = v0;
        short8 v1 = {0, 0, 0, 0, 0, 0, 0, 0};
        if (q == 0) {
            #pragma unroll
            for (int j = 0; j < 8; ++j) v1[j] = f2b(xe[(32 + j) * 64]);
        }
        Bf[1][nt] = v1;
    }

    // ---------------- phase N: nei = adjT * x, BN2 fused on store (f32x4 tbl)
    #pragma unroll
    for (int mt = 0; mt < 3; ++mt) {
        const short* arow = adjTt + (mt * 16 + er) * 64 + q * 8;
        short8 A0 = *(const short8*)(arow);
        short8 A1 = *(const short8*)(arow + 32);
        #pragma unroll
        for (int nt = 0; nt < 4; ++nt) {
            f32x4 z = {0.f, 0.f, 0.f, 0.f};
            z = mfma16(A0, Bf[0][nt], z);
            f32x4 acc = mfma16(A1, Bf[1][nt], z);
            int e = nt * 16 + er;
            f32x4 s2 = *(const f32x4*)(bnS2Tt + e * 48 + mt * 16 + q * 4);
            f32x4 o2 = *(const f32x4*)(bnO2Tt + e * 48 + mt * 16 + q * 4);
            #pragma unroll
            for (int r = 0; r < 4; ++r) {
                int f = mt * 16 + q * 4 + r;
                if (f < 40) {
                    float vv = acc[r] * s2[r] + o2[r];
                    *(short*)(buf + swz(f, e * 2)) = f2b(vv);
                }
            }
        }
    }

    // ---------------- phase M: xcur = BN(concat(x,nei)) @ W + b (in place)
    #pragma unroll
    for (int mt = 0; mt < 3; ++mt) {
        f32x4 acc[4];
        #pragma unroll
        for (int nt = 0; nt < 4; ++nt) { f32x4 z = {0.f,0.f,0.f,0.f}; acc[nt] = z; }
        #pragma unroll
        for (int kt = 0; kt < 4; ++kt) {
            short8 A;
            if (kt < 2) {
                int f = mt * 16 + er;
                if (f < 40) {
                    int kb = kt * 32 + q * 8;
                    const float4* xp = (const float4*)(xb + f * 64 + kb);
                    float4 x0 = xp[0], x1 = xp[1];
                    const float4* sp = (const float4*)(bnSxt + f * 64 + kb);
                    const float4* op = (const float4*)(bnOxt + f * 64 + kb);
                    float4 s0 = sp[0], s1 = sp[1], o0 = op[0], o1 = op[1];
                    A[0] = f2b(x0.x * s0.x + o0.x);
                    A[1] = f2b(x0.y * s0.y + o0.y);
                    A[2] = f2b(x0.z * s0.z + o0.z);
                    A[3] = f2b(x0.w * s0.w + o0.w);
                    A[4] = f2b(x1.x * s1.x + o1.x);
                    A[5] = f2b(x1.y * s1.y + o1.y);
                    A[6] = f2b(x1.z * s1.z + o1.z);
                    A[7] = f2b(x1.w * s1.w + o1.w);
                } else {
                    short8 za = {0,0,0,0,0,0,0,0};
                    A = za;
                }
            } else {
                int f = mt * 16 + er;
                A = *(const short8*)(buf + swz(f, (kt - 2) * 64 + q * 16));
            }
            #pragma unroll
            for (int nt = 0; nt < 4; ++nt) {
                short8 B = *(const short8*)(WTt + (nt * 16 + er) * 128 + kt * 32 + q * 8);
                acc[nt] = mfma16(A, B, acc[nt]);
            }
        }
        #pragma unroll
        for (int nt = 0; nt < 4; ++nt) {
            int e = nt * 16 + er;
            f32x4 bt4 = *(const f32x4*)(btTt + e * 48 + mt * 16 + q * 4);
            #pragma unroll
            for (int r = 0; r < 4; ++r) {
                int f = mt * 16 + q * 4 + r;
                if (f < 40) {
                    float vv = acc[nt][r] + bt4[r];
                    *(short*)(buf + swz(f, e * 2)) = f2b(vv);
                }
            }
        }
    }

    __syncthreads();

    // ---------------- gate: M=16 (8 st used), K=2560 split 8 ways over waves
    {
        f32x4 g0 = {0.f,0.f,0.f,0.f}, g1 = g0, g2 = g0;
        const char* abase = smem + (er & 7) * 6144;
        #pragma unroll
        for (int kk = 0; kk < 10; ++kk) {
            int step = w * 10 + kk;
            int k0 = step * 32;
            int f = k0 >> 6;
            short8 A = *(const short8*)(abase + swz(f, (k0 & 63) * 2 + q * 16));
            const short* gwp = gwT + k0 + q * 8;
            g0 = mfma16(A, *(const short8*)(gwp + er * 2560), g0);
            g1 = mfma16(A, *(const short8*)(gwp + (16 + er) * 2560), g1);
            g2 = mfma16(A, *(const short8*)(gwp + (32 + er) * 2560), g2);
        }
        gred[(w * 3 + 0) * 64 + lane] = g0;
        gred[(w * 3 + 1) * 64 + lane] = g1;
        gred[(w * 3 + 2) * 64 + lane] = g2;
    }
    __syncthreads();

    // reduce 8 wave partials; thread (nt, lane) for tid < 192
    if (tid < 192) {
        int nt = tid >> 6, l = tid & 63;
        int rer = l & 15, rq = l >> 4;
        f32x4 v = gred[(0 * 3 + nt) * 64 + l];
        #pragma unroll
        for (int ww = 1; ww < 8; ++ww) v += gred[(ww * 3 + nt) * 64 + l];
        int fo = nt * 16 + rer;
        if (rq < 2 && fo < 40) {
            float gb = gate_b[fo];
            #pragma unroll
            for (int r = 0; r < 4; ++r)
                g_lds[(rq * 4 + r) * 40 + fo] = v[r] + gb;
        }
    }
    __syncthreads();

    // ---------------- final: softmax over f + weighted sum; thread = (st, e)
    {
        int st = tid >> 6, e = tid & 63;
        const float* gr = g_lds + st * 40;
        const char* bufr = smem + st * 6144;
        float m = gr[0];
        #pragma unroll
        for (int f2 = 1; f2 < 40; ++f2) m = fmaxf(m, gr[f2]);
        float den = 0.f, o = 0.f;
        #pragma unroll
        for (int f2 = 0; f2 < 40; ++f2) {
            float p = __expf(gr[f2] - m);
            den += p;
            short xv = *(const short*)(bufr + swz(f2, e * 2));
            o += p * b2f(xv);
        }
        out[(size_t)(bbase * 2 + st) * 64 + e] = o / den;
    }
}

extern "C" void kernel_launch(void* const* d_in, const int* in_sizes, int n_in,
                              void* d_out, int out_size, void* d_ws, size_t ws_size,
                              hipStream_t stream) {
    (void)in_sizes; (void)n_in; (void)out_size; (void)ws_size;
    const float* x        = (const float*)d_in[0];
    const float* masker   = (const float*)d_in[1];
    const float* ln_gamma = (const float*)d_in[2];
    const float* ln_beta  = (const float*)d_in[3];
    const float* w_t      = (const float*)d_in[4];
    const float* b_t      = (const float*)d_in[5];
    const float* bn_gamma = (const float*)d_in[6];
    const float* bn_beta  = (const float*)d_in[7];
    const float* bn_mean  = (const float*)d_in[8];
    const float* bn_var   = (const float*)d_in[9];
    const float* gate_w   = (const float*)d_in[10];
    const float* gate_b   = (const float*)d_in[11];
    float* out = (float*)d_out;

    short* adjT  = (short*)d_ws;
    short* WT    = adjT + 6144;
    short* gwT   = WT + 16384;
    float* bnSx  = (float*)(gwT + 122880);
    float* bnOx  = bnSx + 5120;
    float* bnS2T = bnOx + 5120;
    float* bnO2T = bnS2T + 6144;
    float* btT   = bnO2T + 6144;

    adj_kernel<<<Tdim, 64, 0, stream>>>(masker, ln_gamma, ln_beta, adjT);
    prep_kernel<<<612, 256, 0, stream>>>(w_t, gate_w, bn_gamma, bn_beta, bn_mean,
                                         bn_var, b_t, WT, gwT, bnSx, bnOx,
                                         bnS2T, bnO2T, btT);

    constexpr int SMEM_BYTES = 8 * 6144 + 24 * 64 * 16 + 8 * 40 * 4;  // 75008
    (void)hipFuncSetAttribute((const void*)main_kernel,
                              hipFuncAttributeMaxDynamicSharedMemorySize, SMEM_BYTES);
    main_kernel<<<1024, 512, SMEM_BYTES, stream>>>(
        x, adjT, WT, gwT, bnSx, bnOx, bnS2T, bnO2T, btT, gate_b, out);
}

// Round 6
// 72.985 us; speedup vs baseline: 2.0704x; 2.0680x over previous
//
#include <hip/hip_runtime.h>
#include <hip/hip_bf16.h>
#include <math.h>

#define Fdim 40
#define Edim 64
#define Tdim 2
#define EPSV 1e-5f

typedef __attribute__((ext_vector_type(8))) short short8;
typedef __attribute__((ext_vector_type(4))) float f32x4;

__device__ __forceinline__ short f2b(float f) {
    unsigned u = __builtin_bit_cast(unsigned, f);
    unsigned r = (u + 0x7fffu + ((u >> 16) & 1u)) >> 16;
    return (short)r;
}
__device__ __forceinline__ float b2f(short h) {
    unsigned u = ((unsigned)(unsigned short)h) << 16;
    return __builtin_bit_cast(float, u);
}
__device__ __forceinline__ f32x4 mfma16(short8 a, short8 b, f32x4 c) {
    return __builtin_amdgcn_mfma_f32_16x16x32_bf16(a, b, c, 0, 0, 0);
}
// swizzled byte offset within a [40][64] bf16 buffer (row stride 128 B)
__device__ __forceinline__ int swz(int f, int e2 /*byte col*/) {
    return (f * 128 + e2) ^ ((f & 7) << 4);
}

// ws layout (fragment-major, [frag][lane] so loads are base + lane*16):
//   adjF  bf16 [2][3][2][64]x8     : shorts 0      .. 6144
//   WF    bf16 [2][4][4][64]x8     : shorts 6144   .. 22528
//   gwF   bf16 [80][3][64]x8       : shorts 22528  .. 145408
//   bnSxF f32  [2][3][2][2][64]x4  : 6144 f32
//   bnOxF f32  same                : 6144 f32
//   bn2SF f32  [2][3][4][64]x4     : 6144 f32
//   bn2OF f32  same                : 6144 f32
//   btF   f32  [2][3][4][64]x4     : 6144 f32      (total 413696 B)

// ---------------------------------------------------------------------------
// adjacency -> A-operand fragments adjF
// ---------------------------------------------------------------------------
__global__ void adj_kernel(const float* __restrict__ masker,
                           const float* __restrict__ ln_gamma,
                           const float* __restrict__ ln_beta,
                           short* __restrict__ adjF) {
    const int t = blockIdx.x;
    const int tid = threadIdx.x;
    __shared__ float araw[Fdim][Fdim];

    for (int i = tid; i < Fdim * Fdim; i += 64) {
        int g = i / Fdim, ff = i % Fdim;
        const float* mb = masker + t * (3 * Fdim * Fdim) + g * Fdim + ff;
        float p = mb[0] * mb[Fdim * Fdim] * mb[2 * Fdim * Fdim];
        araw[g][ff] = p > 0.f ? p : 0.f;
    }
    __syncthreads();

    const int f = tid;
    float vals[Fdim];
    if (f < 40) {
        float mu = 0.f, m2 = 0.f;
        #pragma unroll
        for (int g = 0; g < Fdim; ++g) {
            float v = araw[g][f];
            mu += v; m2 += v * v;
        }
        mu *= (1.f / Fdim); m2 *= (1.f / Fdim);
        float inv = rsqrtf(m2 - mu * mu + EPSV);

        float mx = -1e30f;
        #pragma unroll
        for (int g = 0; g < Fdim; ++g) {
            float v = araw[g][f];
            float l = (v - mu) * inv * ln_gamma[g] + ln_beta[g];
            if (v == 0.f) l += -1e9f;
            if (g == f) l += 1.f;
            vals[g] = l;
            mx = fmaxf(mx, l);
        }
        float den = 0.f;
        #pragma unroll
        for (int g = 0; g < Fdim; ++g) {
            float p = expf(vals[g] - mx);
            vals[g] = p;
            den += p;
        }
        float rden = 1.f / den;
        #pragma unroll
        for (int g = 0; g < Fdim; ++g) {
            float msk = (araw[g][f] != 0.f) ? 1.f : 0.f;
            vals[g] = vals[g] * rden * msk;   // adjT[f][g]
        }
    }
    if (f < 48) {
        int er = f & 15, mt = f >> 4;
        short8* dst = (short8*)adjF;
        #pragma unroll
        for (int kt = 0; kt < 2; ++kt) {
            #pragma unroll
            for (int qq = 0; qq < 4; ++qq) {
                short8 v;
                #pragma unroll
                for (int j = 0; j < 8; ++j) {
                    int g = kt * 32 + qq * 8 + j;
                    v[j] = (f < 40 && g < 40) ? f2b(vals[g]) : (short)0;
                }
                dst[((t * 3 + mt) * 2 + kt) * 64 + qq * 16 + er] = v;
            }
        }
    }
}

// ---------------------------------------------------------------------------
// prep: all weight/table streams rewritten fragment-major ([frag][lane])
// ---------------------------------------------------------------------------
__global__ void prep_kernel(const float* __restrict__ w_t,
                            const float* __restrict__ gate_w,
                            const float* __restrict__ bn_gamma,
                            const float* __restrict__ bn_beta,
                            const float* __restrict__ bn_mean,
                            const float* __restrict__ bn_var,
                            const float* __restrict__ b_t,
                            short* __restrict__ WF,
                            short* __restrict__ gwF,
                            float* __restrict__ bnSxF,
                            float* __restrict__ bnOxF,
                            float* __restrict__ bn2SF,
                            float* __restrict__ bn2OF,
                            float* __restrict__ btF) {
    int i = blockIdx.x * 256 + threadIdx.x;
    if (i < 16384) {
        int j = i & 7, l = (i >> 3) & 63, nt = (i >> 9) & 3, kt = (i >> 11) & 3, t = i >> 13;
        int k = kt * 32 + (l >> 4) * 8 + j, e = nt * 16 + (l & 15);
        WF[i] = f2b(w_t[t * 8192 + k * 64 + e]);
    } else if (i < 139264) {
        int idx = i - 16384;
        int j = idx & 7, l = (idx >> 3) & 63, r = idx >> 9;
        int nt = r % 3, kk = r / 3;
        int fo = nt * 16 + (l & 15), k = kk * 32 + (l >> 4) * 8 + j;
        gwF[idx] = (fo < 40) ? f2b(gate_w[(size_t)k * 40 + fo]) : (short)0;
    } else if (i < 145408) {                 // bnx: x-half BN tables
        int idx = i - 139264;
        int c = idx & 3, l = (idx >> 2) & 63, h = (idx >> 8) & 1, kt = (idx >> 9) & 1, tm = idx >> 10;
        int mt = tm % 3, t = tm / 3;
        int f = mt * 16 + (l & 15), k = kt * 32 + (l >> 4) * 8 + h * 4 + c;
        float sv = 0.f, ov = 0.f;
        if (f < 40) {
            int src = t * 5120 + f * 128 + k;
            sv = bn_gamma[src] * rsqrtf(bn_var[src] + EPSV);
            ov = bn_beta[src] - bn_mean[src] * sv;
        }
        bnSxF[idx] = sv; bnOxF[idx] = ov;
    } else if (i < 151552) {                 // bn2: nei-half BN tables
        int idx = i - 145408;
        int rr = idx & 3, l = (idx >> 2) & 63, nt = (idx >> 8) & 3, tm = idx >> 10;
        int mt = tm % 3, t = tm / 3;
        int f = mt * 16 + (l >> 4) * 4 + rr, e = nt * 16 + (l & 15);
        float sv = 0.f, ov = 0.f;
        if (f < 40) {
            int src = t * 5120 + f * 128 + 64 + e;
            sv = bn_gamma[src] * rsqrtf(bn_var[src] + EPSV);
            ov = bn_beta[src] - bn_mean[src] * sv;
        }
        bn2SF[idx] = sv; bn2OF[idx] = ov;
    } else if (i < 157696) {                 // btF: bias table
        int idx = i - 151552;
        int rr = idx & 3, l = (idx >> 2) & 63, nt = (idx >> 8) & 3, tm = idx >> 10;
        int mt = tm % 3, t = tm / 3;
        int f = mt * 16 + (l >> 4) * 4 + rr, e = nt * 16 + (l & 15);
        btF[idx] = (f < 40) ? b_t[t * 2560 + f * 64 + e] : 0.f;
    }
}

// ---------------------------------------------------------------------------
// main: 512 thr / 8 waves; wave w = (s = w>>1, t = w&1), sample = blockIdx*4+s.
// Per-wave LDS buf 5152 B ([40][64] bf16 swizzled, bank-shift pad).
// LDS total 53824 B -> 2 blocks/CU (16 waves). All weight loads coalesced.
// ---------------------------------------------------------------------------
__global__ __launch_bounds__(512, 4) void main_kernel(
    const float* __restrict__ x,
    const short* __restrict__ adjF,
    const short* __restrict__ WF,
    const short* __restrict__ gwF,
    const f32x4* __restrict__ bnSxF,
    const f32x4* __restrict__ bnOxF,
    const f32x4* __restrict__ bn2SF,
    const f32x4* __restrict__ bn2OF,
    const f32x4* __restrict__ btF,
    const float* __restrict__ gate_b,
    float* __restrict__ out)
{
    extern __shared__ char smem[];
    const int tid = threadIdx.x;
    const int w = tid >> 6, lane = tid & 63;
    const int er = lane & 15, q = lane >> 4;
    const int s = w >> 1, t = w & 1;
    const int bbase = blockIdx.x * 4;

    char* buf = smem + w * 5152;                 // this wave's [40][64] swz buf
    f32x4* gred = (f32x4*)(smem + 41216);        // [4][3][64] f32x4 = 12288 B
    float* g_lds = (float*)(smem + 53504);       // [8][40] f32

    const float* xb = x + (size_t)(bbase + s) * 2560;
    const short8* adjF8 = (const short8*)adjF;
    const short8* WF8   = (const short8*)WF;
    const short8* gwF8  = (const short8*)gwF;

    // ---- build B-fragments of x (k = g): global gather, 4 lines/instr
    short8 Bf[2][4];
    #pragma unroll
    for (int nt = 0; nt < 4; ++nt) {
        const float* xe = xb + nt * 16 + er;
        short8 v0;
        #pragma unroll
        for (int j = 0; j < 8; ++j) v0[j] = f2b(xe[(q * 8 + j) * 64]);
        Bf[0][nt] = v0;
        short8 v1 = {0, 0, 0, 0, 0, 0, 0, 0};
        if (q == 0) {
            #pragma unroll
            for (int j = 0; j < 8; ++j) v1[j] = f2b(xe[(32 + j) * 64]);
        }
        Bf[1][nt] = v1;
    }

    // ---------------- phase N: nei = adjT * x, BN2 fused on store
    #pragma unroll
    for (int mt = 0; mt < 3; ++mt) {
        short8 A0 = adjF8[((t * 3 + mt) * 2 + 0) * 64 + lane];
        short8 A1 = adjF8[((t * 3 + mt) * 2 + 1) * 64 + lane];
        #pragma unroll
        for (int nt = 0; nt < 4; ++nt) {
            f32x4 z = {0.f, 0.f, 0.f, 0.f};
            z = mfma16(A0, Bf[0][nt], z);
            f32x4 acc = mfma16(A1, Bf[1][nt], z);
            f32x4 s2 = bn2SF[((t * 3 + mt) * 4 + nt) * 64 + lane];
            f32x4 o2 = bn2OF[((t * 3 + mt) * 4 + nt) * 64 + lane];
            int e = nt * 16 + er;
            #pragma unroll
            for (int r = 0; r < 4; ++r) {
                int f = mt * 16 + q * 4 + r;
                if (f < 40) {
                    float vv = acc[r] * s2[r] + o2[r];
                    *(short*)(buf + swz(f, e * 2)) = f2b(vv);
                }
            }
        }
    }

    // ---------------- phase M: xcur = BN(concat(x,nei)) @ W + b (in place)
    #pragma unroll
    for (int mt = 0; mt < 3; ++mt) {
        f32x4 acc[4];
        #pragma unroll
        for (int nt = 0; nt < 4; ++nt) { f32x4 z = {0.f,0.f,0.f,0.f}; acc[nt] = z; }
        #pragma unroll
        for (int kt = 0; kt < 4; ++kt) {
            short8 A;
            if (kt < 2) {
                int f = mt * 16 + er;
                if (f < 40) {
                    const float4* xp = (const float4*)(xb + f * 64 + kt * 32 + q * 8);
                    float4 x0 = xp[0], x1 = xp[1];
                    int fb = (((t * 3 + mt) * 2 + kt) * 2) * 64 + lane;
                    f32x4 s0 = bnSxF[fb], s1 = bnSxF[fb + 64];
                    f32x4 o0 = bnOxF[fb], o1 = bnOxF[fb + 64];
                    A[0] = f2b(x0.x * s0[0] + o0[0]);
                    A[1] = f2b(x0.y * s0[1] + o0[1]);
                    A[2] = f2b(x0.z * s0[2] + o0[2]);
                    A[3] = f2b(x0.w * s0[3] + o0[3]);
                    A[4] = f2b(x1.x * s1[0] + o1[0]);
                    A[5] = f2b(x1.y * s1[1] + o1[1]);
                    A[6] = f2b(x1.z * s1[2] + o1[2]);
                    A[7] = f2b(x1.w * s1[3] + o1[3]);
                } else {
                    short8 za = {0,0,0,0,0,0,0,0};
                    A = za;
                }
            } else {
                int f = mt * 16 + er;   // rows 40..47 read garbage: discarded D rows
                A = *(const short8*)(buf + swz(f, (kt - 2) * 64 + q * 16));
            }
            #pragma unroll
            for (int nt = 0; nt < 4; ++nt) {
                short8 B = WF8[((t * 4 + kt) * 4 + nt) * 64 + lane];
                acc[nt] = mfma16(A, B, acc[nt]);
            }
        }
        #pragma unroll
        for (int nt = 0; nt < 4; ++nt) {
            f32x4 bt4 = btF[((t * 3 + mt) * 4 + nt) * 64 + lane];
            int e = nt * 16 + er;
            #pragma unroll
            for (int r = 0; r < 4; ++r) {
                int f = mt * 16 + q * 4 + r;
                if (f < 40) {
                    float vv = acc[nt][r] + bt4[r];
                    *(short*)(buf + swz(f, e * 2)) = f2b(vv);
                }
            }
        }
    }

    __syncthreads();

    // ---------------- gate: M=16 (8 st used), K=2560 split 8 ways over waves
    f32x4 g0 = {0.f,0.f,0.f,0.f}, g1 = g0, g2 = g0;
    {
        const char* abase = smem + (er & 7) * 5152;
        #pragma unroll
        for (int kk = 0; kk < 10; ++kk) {
            int step = w * 10 + kk;
            int k0 = step * 32;
            int f = k0 >> 6;
            short8 A = *(const short8*)(abase + swz(f, (k0 & 63) * 2 + q * 16));
            const short8* gp = gwF8 + (size_t)step * 3 * 64 + lane;
            g0 = mfma16(A, gp[0], g0);
            g1 = mfma16(A, gp[64], g1);
            g2 = mfma16(A, gp[128], g2);
        }
    }
    if (w < 4) {
        gred[(w * 3 + 0) * 64 + lane] = g0;
        gred[(w * 3 + 1) * 64 + lane] = g1;
        gred[(w * 3 + 2) * 64 + lane] = g2;
    }
    __syncthreads();
    if (w >= 4) {
        gred[((w - 4) * 3 + 0) * 64 + lane] += g0;
        gred[((w - 4) * 3 + 1) * 64 + lane] += g1;
        gred[((w - 4) * 3 + 2) * 64 + lane] += g2;
    }
    __syncthreads();

    // reduce 4 buffers; thread (nt, lane) for tid < 192
    if (tid < 192) {
        int nt = tid >> 6, l = tid & 63;
        int rer = l & 15, rq = l >> 4;
        f32x4 v = gred[(0 * 3 + nt) * 64 + l];
        #pragma unroll
        for (int ww = 1; ww < 4; ++ww) v += gred[(ww * 3 + nt) * 64 + l];
        int fo = nt * 16 + rer;
        if (rq < 2 && fo < 40) {
            float gb = gate_b[fo];
            #pragma unroll
            for (int r = 0; r < 4; ++r)
                g_lds[(rq * 4 + r) * 40 + fo] = v[r] + gb;
        }
    }
    __syncthreads();

    // ---------------- final: softmax over f + weighted sum; thread = (st, e)
    {
        int st = tid >> 6, e = tid & 63;
        const float* gr = g_lds + st * 40;
        const char* bufr = smem + st * 5152;
        float m = gr[0];
        #pragma unroll
        for (int f2 = 1; f2 < 40; ++f2) m = fmaxf(m, gr[f2]);
        float den = 0.f, o = 0.f;
        #pragma unroll
        for (int f2 = 0; f2 < 40; ++f2) {
            float p = __expf(gr[f2] - m);
            den += p;
            short xv = *(const short*)(bufr + swz(f2, e * 2));
            o += p * b2f(xv);
        }
        out[(size_t)(bbase * 2 + st) * 64 + e] = o / den;
    }
}

extern "C" void kernel_launch(void* const* d_in, const int* in_sizes, int n_in,
                              void* d_out, int out_size, void* d_ws, size_t ws_size,
                              hipStream_t stream) {
    (void)in_sizes; (void)n_in; (void)out_size; (void)ws_size;
    const float* x        = (const float*)d_in[0];
    const float* masker   = (const float*)d_in[1];
    const float* ln_gamma = (const float*)d_in[2];
    const float* ln_beta  = (const float*)d_in[3];
    const float* w_t      = (const float*)d_in[4];
    const float* b_t      = (const float*)d_in[5];
    const float* bn_gamma = (const float*)d_in[6];
    const float* bn_beta  = (const float*)d_in[7];
    const float* bn_mean  = (const float*)d_in[8];
    const float* bn_var   = (const float*)d_in[9];
    const float* gate_w   = (const float*)d_in[10];
    const float* gate_b   = (const float*)d_in[11];
    float* out = (float*)d_out;

    short* adjFp  = (short*)d_ws;
    short* WFp    = adjFp + 6144;
    short* gwFp   = WFp + 16384;
    float* bnSxFp = (float*)(gwFp + 122880);
    float* bnOxFp = bnSxFp + 6144;
    float* bn2SFp = bnOxFp + 6144;
    float* bn2OFp = bn2SFp + 6144;
    float* btFp   = bn2OFp + 6144;

    adj_kernel<<<Tdim, 64, 0, stream>>>(masker, ln_gamma, ln_beta, adjFp);
    prep_kernel<<<616, 256, 0, stream>>>(w_t, gate_w, bn_gamma, bn_beta, bn_mean,
                                         bn_var, b_t, WFp, gwFp, bnSxFp, bnOxFp,
                                         bn2SFp, bn2OFp, btFp);

    constexpr int SMEM_BYTES = 8 * 5152 + 12288 + 320;  // 53824
    main_kernel<<<1024, 512, SMEM_BYTES, stream>>>(
        x, adjFp, (const short*)WFp, (const short*)gwFp,
        (const f32x4*)bnSxFp, (const f32x4*)bnOxFp,
        (const f32x4*)bn2SFp, (const f32x4*)bn2OFp,
        (const f32x4*)btFp, gate_b, out);
}